// Round 7
// baseline (157.448 us; speedup 1.0000x reference)
//
#include <hip/hip_runtime.h>
#include <hip/hip_bf16.h>
#include <math.h>

// Problem constants (from reference)
#define BATCH   2
#define SEQ     512     // N
#define DIN     512
#define DM      256     // d_model

#define LOG2E2  2.88539008177792681f   // 2*log2(e)

#if __has_builtin(__builtin_amdgcn_exp2f)
#define EXP2(x) __builtin_amdgcn_exp2f(x)
#else
#define EXP2(x) exp2f(x)
#endif
#if __has_builtin(__builtin_amdgcn_rcpf)
#define RCP(x) __builtin_amdgcn_rcpf(x)
#else
#define RCP(x) (1.0f / (x))
#endif

// tanh(t) with targ = 2*log2(e)*t: tanh = 1 - 2/(1 + exp2(targ)); overflow-safe.
__device__ __forceinline__ float tanh_from_scaled(float targ) {
    return fmaf(-2.0f, RCP(1.0f + EXP2(targ)), 1.0f);
}

#define EB_BLOCKS  (BATCH * DM)            // 512: EB transposed writer
#define EA_BLOCKS  ((BATCH * SEQ) / 2)     // 512: EA row-major writer (2 rows/block)
#define H_BLOCKS   ((BATCH * SEQ) / 4)     // 256: h GEMM (4 rows/block)

// ---------------- Kernel 1: EB (transposed) + EA (row-major) + h = tanh(x@Wx+bx) ----
// 512 threads/block, three grid segments.
__global__ __launch_bounds__(512) void prep_kernel(
    const float* __restrict__ pos,   // [B, N, 4]
    const float* __restrict__ Wp,    // [4, DM]
    const float* __restrict__ bp,    // [DM]
    const float* __restrict__ x,     // [B*N, DIN]
    const float* __restrict__ Wx,    // [DIN, DM]
    const float* __restrict__ bx,    // [DM]
    float* __restrict__ EA,          // [B*N, DM]   row-major (for scalar streams)
    float* __restrict__ EB,          // [B][DM][SEQ] (for coalesced vector loads)
    float* __restrict__ h)           // [B*N, DM]
{
    const int tid = threadIdx.x;

    if (blockIdx.x < EB_BLOCKS) {
        // ---- EB part: block = (b, d), thread = n; coalesced store ----
        const int b = blockIdx.x >> 8;
        const int d = blockIdx.x & 255;
        const int n = tid;

        const float wp0 = Wp[d];            // uniform -> s_load
        const float wp1 = Wp[DM + d];
        const float wp2 = Wp[2*DM + d];
        const float wp3 = Wp[3*DM + d];

        const float4 p = ((const float4*)pos)[b * SEQ + n];   // coalesced 16B
        const float P = fmaf(p.x, wp0, fmaf(p.y, wp1, fmaf(p.z, wp2, p.w * wp3)));
        EB[((size_t)(b * DM + d)) * SEQ + n] = EXP2(-LOG2E2 * P);
        return;
    }

    if (blockIdx.x < EB_BLOCKS + EA_BLOCKS) {
        // ---- EA part: block = 2 rows, thread = (il = tid>>8, d = tid&255); coalesced ----
        const int idx = blockIdx.x - EB_BLOCKS;
        const int b   = idx >> 8;
        const int ip  = idx & 255;
        const int il  = __builtin_amdgcn_readfirstlane(tid >> 8);   // wave-uniform
        const int d   = tid & 255;
        const int bi  = b * SEQ + ip * 2 + il;

        const float4 p = ((const float4*)pos)[bi];   // uniform -> s_load
        const float P = fmaf(p.x, Wp[d],
                        fmaf(p.y, Wp[DM + d],
                        fmaf(p.z, Wp[2*DM + d],
                             p.w * Wp[3*DM + d])));
        EA[(size_t)bi * DM + d] = EXP2(LOG2E2 * (P + bp[d]));   // coalesced
        return;
    }

    // ---- h part: 4 rows/block, wave w = (r = w&3, half = w>>2) ----
    __shared__ float4 s_x[4][DIN/4];     // 8 KB
    __shared__ float4 s_part[4][64];     // 4 KB

    const int w    = tid >> 6;
    const int l    = tid & 63;
    const int r    = w & 3;
    const int half = w >> 2;
    const int row  = (blockIdx.x - EB_BLOCKS - EA_BLOCKS) * 4 + r;

    const float4* __restrict__ xr = (const float4*)(x + (size_t)row * DIN);
    s_x[r][half * 64 + l] = xr[half * 64 + l];
    __syncthreads();

    float4 acc = half ? make_float4(0.f, 0.f, 0.f, 0.f) : ((const float4*)bx)[l];
    const float* __restrict__ wxp = Wx + 4 * l;

    #pragma unroll 2
    for (int k4 = 0; k4 < 64; k4++) {
        const int kk = half * 64 + k4;
        const float4 xv = s_x[r][kk];                     // ds_read_b128 broadcast
        const float4 w0 = *(const float4*)(wxp + (size_t)(4*kk + 0) * DM);
        const float4 w1 = *(const float4*)(wxp + (size_t)(4*kk + 1) * DM);
        const float4 w2 = *(const float4*)(wxp + (size_t)(4*kk + 2) * DM);
        const float4 w3 = *(const float4*)(wxp + (size_t)(4*kk + 3) * DM);
        acc.x = fmaf(xv.x, w0.x, acc.x); acc.y = fmaf(xv.x, w0.y, acc.y);
        acc.z = fmaf(xv.x, w0.z, acc.z); acc.w = fmaf(xv.x, w0.w, acc.w);
        acc.x = fmaf(xv.y, w1.x, acc.x); acc.y = fmaf(xv.y, w1.y, acc.y);
        acc.z = fmaf(xv.y, w1.z, acc.z); acc.w = fmaf(xv.y, w1.w, acc.w);
        acc.x = fmaf(xv.z, w2.x, acc.x); acc.y = fmaf(xv.z, w2.y, acc.y);
        acc.z = fmaf(xv.z, w2.z, acc.z); acc.w = fmaf(xv.z, w2.w, acc.w);
        acc.x = fmaf(xv.w, w3.x, acc.x); acc.y = fmaf(xv.w, w3.y, acc.y);
        acc.z = fmaf(xv.w, w3.z, acc.z); acc.w = fmaf(xv.w, w3.w, acc.w);
    }

    if (half) s_part[r][l] = acc;
    __syncthreads();
    if (!half) {
        const float4 q = s_part[r][l];
        float4 t;
        t.x = tanh_from_scaled(LOG2E2 * (acc.x + q.x));
        t.y = tanh_from_scaled(LOG2E2 * (acc.y + q.y));
        t.z = tanh_from_scaled(LOG2E2 * (acc.z + q.z));
        t.w = tanh_from_scaled(LOG2E2 * (acc.w + q.w));
        ((float4*)(h + (size_t)row * DM))[l] = t;
    }
}

// ---------------- Kernel 2: scores + softmax + weighted sum ----------------
// grid = B*N/4 = 256 blocks (4 i-rows each), 1024 threads (16 waves).
// Phase 1/2: wave w -> (row = w&3, j-quarter = w>>2); thread owns 2 consecutive j.
// EA row + wv stream through the SCALAR pipe (wave-uniform, readfirstlane-forced);
// phase 1 issues ZERO LDS instructions.
__global__ __launch_bounds__(1024) void attn_kernel(
    const int*   __restrict__ mask,  // [B, N, N]
    const float* __restrict__ wv,    // [DM]
    const float* __restrict__ EA,    // [B*N, DM]
    const float* __restrict__ EB,    // [B][DM][SEQ]
    const float* __restrict__ h,     // [B, N, DM]
    float* __restrict__ out,         // [B, N, DM]
    float* __restrict__ attn_out)    // [B, N, N]
{
    const int b   = blockIdx.x >> 7;      // 128 blocks per batch
    const int i0  = (blockIdx.x & 127) * 4;
    const int tid = threadIdx.x;          // 0..1023
    const int l   = tid & 63;
    const int w   = __builtin_amdgcn_readfirstlane(tid >> 6);  // 0..15, SGPR
    const int row = w & 3;                // local row 0..3
    const int jh  = w >> 2;               // j-quarter 0..3
    const int j0  = jh * 128 + l * 2;     // first of this thread's 2 j

    __shared__ float s_p[4][SEQ];         // 8 KB
    __shared__ float s_part[4][DM];       // 4 KB
    __shared__ float s_red[4][4];

    // ---- phase 1: a_r[j] = sum_d w_d / (1 + EA[row,d]*EB[d,j]) ----
    // score = const - 2a (softmax shift-invariant).
    const float* __restrict__ EArow = EA + (size_t)(b * SEQ + i0 + row) * DM;  // uniform
    const float2* __restrict__ EBj  = (const float2*)(EB + (size_t)b * DM * SEQ + j0);

    float a0 = 0.f, a1 = 0.f;
    #pragma unroll 8
    for (int d = 0; d < DM; d++) {
        const float2 eb = EBj[(size_t)d * (SEQ/2)];   // coalesced dwordx2 (L2)
        const float  ea = EArow[d];                   // s_load stream
        const float  wd = wv[d];                      // s_load stream
        a0 = fmaf(wd, RCP(fmaf(ea, eb.x, 1.0f)), a0);
        a1 = fmaf(wd, RCP(fmaf(ea, eb.y, 1.0f)), a1);
    }

    // ---- phase 2: masked softmax, no max-shift (exponents O(1), fp32-safe) ----
    const size_t mrow = (size_t)b * SEQ * SEQ + (size_t)(i0 + row) * SEQ + j0;
    const int2 m = *(const int2*)(mask + mrow);

    float p0 = m.x ? EXP2(-LOG2E2 * a0) : 0.f;
    float p1 = m.y ? EXP2(-LOG2E2 * a1) : 0.f;

    float s = p0 + p1;
    #pragma unroll
    for (int off = 32; off; off >>= 1) s += __shfl_xor(s, off, 64);
    if (l == 0) s_red[row][jh] = s;
    __syncthreads();

    const float4 rs = *(const float4*)s_red[row];
    const float inv = __fdividef(1.0f, (rs.x + rs.y) + (rs.z + rs.w));
    p0 *= inv;
    p1 *= inv;

    *(float2*)(attn_out + mrow) = make_float2(p0, p1);
    *(float2*)(&s_p[row][j0])   = make_float2(p0, p1);
    __syncthreads();

    // ---- phase 3: out[i_r,d] = sum_j p_r[j] * h[b,j,d], all 16 waves ----
    // thread = (d = tid&255, g = tid>>8): rows {rp, rp+2}, j-half = g>>1.
    const int g  = __builtin_amdgcn_readfirstlane(tid >> 8);   // 0..3
    const int rp = g & 1;
    const int j2 = g >> 1;
    const float* __restrict__ hj = h + (size_t)b * SEQ * DM + (size_t)(j2 * 256) * DM + (tid & 255);
    const float4* __restrict__ pA = (const float4*)&s_p[rp][j2 * 256];
    const float4* __restrict__ pB = (const float4*)&s_p[rp + 2][j2 * 256];

    float accA = 0.f, accB = 0.f;
    #pragma unroll 4
    for (int q = 0; q < 64; q++) {
        const float4 qA = pA[q];
        const float4 qB = pB[q];
        const float h0 = hj[(size_t)(4*q + 0) * DM];
        const float h1 = hj[(size_t)(4*q + 1) * DM];
        const float h2 = hj[(size_t)(4*q + 2) * DM];
        const float h3 = hj[(size_t)(4*q + 3) * DM];
        accA = fmaf(qA.x, h0, fmaf(qA.y, h1, fmaf(qA.z, h2, fmaf(qA.w, h3, accA))));
        accB = fmaf(qB.x, h0, fmaf(qB.y, h1, fmaf(qB.z, h2, fmaf(qB.w, h3, accB))));
    }

    const int d = tid & 255;
    if (j2 == 1) {
        s_part[rp][d]     = accA;
        s_part[rp + 2][d] = accB;
    }
    __syncthreads();
    if (j2 == 0) {
        out[(size_t)(b * SEQ + i0 + rp) * DM + d]     = accA + s_part[rp][d];
        out[(size_t)(b * SEQ + i0 + rp + 2) * DM + d] = accB + s_part[rp + 2][d];
    }
}

extern "C" void kernel_launch(void* const* d_in, const int* in_sizes, int n_in,
                              void* d_out, int out_size, void* d_ws, size_t ws_size,
                              hipStream_t stream) {
    const float* x    = (const float*)d_in[0];
    const float* pos  = (const float*)d_in[1];
    const int*   mask = (const int*)  d_in[2];
    const float* Wx   = (const float*)d_in[3];
    const float* bx   = (const float*)d_in[4];
    const float* Wp   = (const float*)d_in[5];
    const float* bp   = (const float*)d_in[6];
    const float* wv   = (const float*)d_in[7];

    float* out      = (float*)d_out;                          // [B,N,DM]
    float* attn_out = (float*)d_out + (size_t)BATCH*SEQ*DM;   // [B,N,N]

    char* ws  = (char*)d_ws;
    float* h  = (float*)(ws);                                 // 1 MB
    float* EA = (float*)(ws + (size_t)BATCH*SEQ*DM*4);        // 1 MB
    float* EB = (float*)(ws + 2*(size_t)BATCH*SEQ*DM*4);      // 1 MB

    prep_kernel<<<EB_BLOCKS + EA_BLOCKS + H_BLOCKS, 512, 0, stream>>>(
        pos, Wp, bp, x, Wx, bx, EA, EB, h);
    attn_kernel<<<(BATCH*SEQ)/4, 1024, 0, stream>>>(mask, wv, EA, EB, h, out, attn_out);
}

// Round 8
// 132.846 us; speedup vs baseline: 1.1852x; 1.1852x over previous
//
#include <hip/hip_runtime.h>
#include <hip/hip_bf16.h>
#include <math.h>

// Problem constants (from reference)
#define BATCH   2
#define SEQ     512     // N
#define DIN     512
#define DM      256     // d_model

#define LOG2E2  2.88539008177792681f   // 2*log2(e)

#if __has_builtin(__builtin_amdgcn_exp2f)
#define EXP2(x) __builtin_amdgcn_exp2f(x)
#else
#define EXP2(x) exp2f(x)
#endif
#if __has_builtin(__builtin_amdgcn_rcpf)
#define RCP(x) __builtin_amdgcn_rcpf(x)
#else
#define RCP(x) (1.0f / (x))
#endif

// tanh(t) with targ = 2*log2(e)*t: tanh = 1 - 2/(1 + exp2(targ)); overflow-safe.
__device__ __forceinline__ float tanh_from_scaled(float targ) {
    return fmaf(-2.0f, RCP(1.0f + EXP2(targ)), 1.0f);
}

// ---------------- EB writer: EB[b][d][j] = exp2(-c*pos_j.Wp_d) ----------------
// 512 blocks = (b,d), 512 threads = n. All coalesced.
__global__ __launch_bounds__(512) void eb_w(
    const float* __restrict__ pos, const float* __restrict__ Wp,
    float* __restrict__ EB)
{
    const int b = blockIdx.x >> 8;
    const int d = blockIdx.x & 255;
    const int n = threadIdx.x;

    const float wp0 = Wp[d];            // uniform -> s_load
    const float wp1 = Wp[DM + d];
    const float wp2 = Wp[2*DM + d];
    const float wp3 = Wp[3*DM + d];

    const float4 p = ((const float4*)pos)[b * SEQ + n];   // coalesced 16B
    const float P = fmaf(p.x, wp0, fmaf(p.y, wp1, fmaf(p.z, wp2, p.w * wp3)));
    EB[((size_t)(b * DM + d)) * SEQ + n] = EXP2(-LOG2E2 * P);
}

// ---------------- EA writer: EA[b*N+i][d] = exp2(c*(pos_i.Wp_d + bp_d)) --------
// 1024 blocks = row bi, 256 threads = d. pos uniform s_load; Wp/bp/store coalesced.
__global__ __launch_bounds__(256) void ea_w(
    const float* __restrict__ pos, const float* __restrict__ Wp,
    const float* __restrict__ bp, float* __restrict__ EA)
{
    const int bi = blockIdx.x;
    const int d  = threadIdx.x;

    const float4 p = ((const float4*)pos)[bi];   // uniform -> s_load
    const float P = fmaf(p.x, Wp[d],
                    fmaf(p.y, Wp[DM + d],
                    fmaf(p.z, Wp[2*DM + d],
                         p.w * Wp[3*DM + d])));
    EA[(size_t)bi * DM + d] = EXP2(LOG2E2 * (P + bp[d]));   // coalesced
}

// ---------------- h kernel: h = tanh(x@Wx+bx) ----------------
// 512 blocks (2 rows each), 512 threads: wave w = (r = w&1, kq = w>>1 in 0..3).
// Each wave does a 128-k quarter; partials combined via LDS.
__global__ __launch_bounds__(512) void h_k(
    const float* __restrict__ x,    // [B*N, DIN]
    const float* __restrict__ Wx,   // [DIN, DM]
    const float* __restrict__ bx,   // [DM]
    float* __restrict__ h)          // [B*N, DM]
{
    __shared__ float4 s_x[2][DIN/4];       // 4 KB
    __shared__ float4 s_part[2][3][64];    // 6 KB

    const int tid = threadIdx.x;
    const int w   = tid >> 6;
    const int l   = tid & 63;
    const int r   = w & 1;
    const int kq  = w >> 1;                // 0..3, 128-k quarter
    const int row = blockIdx.x * 2 + r;

    // stage this row's x (each wave loads 1/4 of its row's floats = 32 float4)
    const float4* __restrict__ xr = (const float4*)(x + (size_t)row * DIN);
    s_x[r][kq * 32 + (l & 31)] = xr[kq * 32 + (l & 31)];   // 2-way replicated write, same data
    __syncthreads();

    float4 acc = (kq == 0) ? ((const float4*)bx)[l] : make_float4(0.f, 0.f, 0.f, 0.f);
    const float* __restrict__ wxp = Wx + 4 * l;

    #pragma unroll 2
    for (int k4 = 0; k4 < 32; k4++) {
        const int kk = kq * 32 + k4;
        const float4 xv = s_x[r][kk];                     // ds_read_b128 broadcast
        const float4 w0 = *(const float4*)(wxp + (size_t)(4*kk + 0) * DM);
        const float4 w1 = *(const float4*)(wxp + (size_t)(4*kk + 1) * DM);
        const float4 w2 = *(const float4*)(wxp + (size_t)(4*kk + 2) * DM);
        const float4 w3 = *(const float4*)(wxp + (size_t)(4*kk + 3) * DM);
        acc.x = fmaf(xv.x, w0.x, acc.x); acc.y = fmaf(xv.x, w0.y, acc.y);
        acc.z = fmaf(xv.x, w0.z, acc.z); acc.w = fmaf(xv.x, w0.w, acc.w);
        acc.x = fmaf(xv.y, w1.x, acc.x); acc.y = fmaf(xv.y, w1.y, acc.y);
        acc.z = fmaf(xv.y, w1.z, acc.z); acc.w = fmaf(xv.y, w1.w, acc.w);
        acc.x = fmaf(xv.z, w2.x, acc.x); acc.y = fmaf(xv.z, w2.y, acc.y);
        acc.z = fmaf(xv.z, w2.z, acc.z); acc.w = fmaf(xv.z, w2.w, acc.w);
        acc.x = fmaf(xv.w, w3.x, acc.x); acc.y = fmaf(xv.w, w3.y, acc.y);
        acc.z = fmaf(xv.w, w3.z, acc.z); acc.w = fmaf(xv.w, w3.w, acc.w);
    }

    if (kq) s_part[r][kq - 1][l] = acc;
    __syncthreads();
    if (kq == 0) {
        const float4 q0 = s_part[r][0][l];
        const float4 q1 = s_part[r][1][l];
        const float4 q2 = s_part[r][2][l];
        float4 t;
        t.x = tanh_from_scaled(LOG2E2 * (acc.x + q0.x + q1.x + q2.x));
        t.y = tanh_from_scaled(LOG2E2 * (acc.y + q0.y + q1.y + q2.y));
        t.z = tanh_from_scaled(LOG2E2 * (acc.z + q0.z + q1.z + q2.z));
        t.w = tanh_from_scaled(LOG2E2 * (acc.w + q0.w + q1.w + q2.w));
        ((float4*)(h + (size_t)row * DM))[l] = t;
    }
}

// ---------------- attn: scores + softmax + weighted sum (unchanged from r7) ----
// grid = B*N/4 = 256 blocks (4 i-rows each), 1024 threads (16 waves).
// Phase 1/2: wave w -> (row = w&3, j-quarter = w>>2); thread owns 2 consecutive j.
// EA row + wv stream through the SCALAR pipe; phase 1 issues ZERO LDS instructions.
__global__ __launch_bounds__(1024) void attn_kernel(
    const int*   __restrict__ mask,  // [B, N, N]
    const float* __restrict__ wv,    // [DM]
    const float* __restrict__ EA,    // [B*N, DM]
    const float* __restrict__ EB,    // [B][DM][SEQ]
    const float* __restrict__ h,     // [B, N, DM]
    float* __restrict__ out,         // [B, N, DM]
    float* __restrict__ attn_out)    // [B, N, N]
{
    const int b   = blockIdx.x >> 7;      // 128 blocks per batch
    const int i0  = (blockIdx.x & 127) * 4;
    const int tid = threadIdx.x;          // 0..1023
    const int l   = tid & 63;
    const int w   = __builtin_amdgcn_readfirstlane(tid >> 6);  // 0..15, SGPR
    const int row = w & 3;                // local row 0..3
    const int jh  = w >> 2;               // j-quarter 0..3
    const int j0  = jh * 128 + l * 2;     // first of this thread's 2 j

    __shared__ float s_p[4][SEQ];         // 8 KB
    __shared__ float s_part[4][DM];       // 4 KB
    __shared__ float s_red[4][4];

    // ---- phase 1: a_r[j] = sum_d w_d / (1 + EA[row,d]*EB[d,j]) ----
    const float* __restrict__ EArow = EA + (size_t)(b * SEQ + i0 + row) * DM;  // uniform
    const float2* __restrict__ EBj  = (const float2*)(EB + (size_t)b * DM * SEQ + j0);

    float a0 = 0.f, a1 = 0.f;
    #pragma unroll 8
    for (int d = 0; d < DM; d++) {
        const float2 eb = EBj[(size_t)d * (SEQ/2)];   // coalesced dwordx2 (L2)
        const float  ea = EArow[d];                   // s_load stream
        const float  wd = wv[d];                      // s_load stream
        a0 = fmaf(wd, RCP(fmaf(ea, eb.x, 1.0f)), a0);
        a1 = fmaf(wd, RCP(fmaf(ea, eb.y, 1.0f)), a1);
    }

    // ---- phase 2: masked softmax, no max-shift (exponents O(1), fp32-safe) ----
    const size_t mrow = (size_t)b * SEQ * SEQ + (size_t)(i0 + row) * SEQ + j0;
    const int2 m = *(const int2*)(mask + mrow);

    float p0 = m.x ? EXP2(-LOG2E2 * a0) : 0.f;
    float p1 = m.y ? EXP2(-LOG2E2 * a1) : 0.f;

    float s = p0 + p1;
    #pragma unroll
    for (int off = 32; off; off >>= 1) s += __shfl_xor(s, off, 64);
    if (l == 0) s_red[row][jh] = s;
    __syncthreads();

    const float4 rs = *(const float4*)s_red[row];
    const float inv = __fdividef(1.0f, (rs.x + rs.y) + (rs.z + rs.w));
    p0 *= inv;
    p1 *= inv;

    *(float2*)(attn_out + mrow) = make_float2(p0, p1);
    *(float2*)(&s_p[row][j0])   = make_float2(p0, p1);
    __syncthreads();

    // ---- phase 3: out[i_r,d] = sum_j p_r[j] * h[b,j,d], all 16 waves ----
    const int g  = __builtin_amdgcn_readfirstlane(tid >> 8);   // 0..3
    const int rp = g & 1;
    const int j2 = g >> 1;
    const float* __restrict__ hj = h + (size_t)b * SEQ * DM + (size_t)(j2 * 256) * DM + (tid & 255);
    const float4* __restrict__ pA = (const float4*)&s_p[rp][j2 * 256];
    const float4* __restrict__ pB = (const float4*)&s_p[rp + 2][j2 * 256];

    float accA = 0.f, accB = 0.f;
    #pragma unroll 4
    for (int q = 0; q < 64; q++) {
        const float4 qA = pA[q];
        const float4 qB = pB[q];
        const float h0 = hj[(size_t)(4*q + 0) * DM];
        const float h1 = hj[(size_t)(4*q + 1) * DM];
        const float h2 = hj[(size_t)(4*q + 2) * DM];
        const float h3 = hj[(size_t)(4*q + 3) * DM];
        accA = fmaf(qA.x, h0, fmaf(qA.y, h1, fmaf(qA.z, h2, fmaf(qA.w, h3, accA))));
        accB = fmaf(qB.x, h0, fmaf(qB.y, h1, fmaf(qB.z, h2, fmaf(qB.w, h3, accB))));
    }

    const int d = tid & 255;
    if (j2 == 1) {
        s_part[rp][d]     = accA;
        s_part[rp + 2][d] = accB;
    }
    __syncthreads();
    if (j2 == 0) {
        out[(size_t)(b * SEQ + i0 + rp) * DM + d]     = accA + s_part[rp][d];
        out[(size_t)(b * SEQ + i0 + rp + 2) * DM + d] = accB + s_part[rp + 2][d];
    }
}

extern "C" void kernel_launch(void* const* d_in, const int* in_sizes, int n_in,
                              void* d_out, int out_size, void* d_ws, size_t ws_size,
                              hipStream_t stream) {
    const float* x    = (const float*)d_in[0];
    const float* pos  = (const float*)d_in[1];
    const int*   mask = (const int*)  d_in[2];
    const float* Wx   = (const float*)d_in[3];
    const float* bx   = (const float*)d_in[4];
    const float* Wp   = (const float*)d_in[5];
    const float* bp   = (const float*)d_in[6];
    const float* wv   = (const float*)d_in[7];

    float* out      = (float*)d_out;                          // [B,N,DM]
    float* attn_out = (float*)d_out + (size_t)BATCH*SEQ*DM;   // [B,N,N]

    char* ws  = (char*)d_ws;
    float* h  = (float*)(ws);                                 // 1 MB
    float* EA = (float*)(ws + (size_t)BATCH*SEQ*DM*4);        // 1 MB
    float* EB = (float*)(ws + 2*(size_t)BATCH*SEQ*DM*4);      // 1 MB

    eb_w<<<BATCH*DM, 512, 0, stream>>>(pos, Wp, EB);
    ea_w<<<BATCH*SEQ, 256, 0, stream>>>(pos, Wp, bp, EA);
    h_k <<<(BATCH*SEQ)/2, 512, 0, stream>>>(x, Wx, bx, h);
    attn_kernel<<<(BATCH*SEQ)/4, 1024, 0, stream>>>(mask, wv, EA, EB, h, out, attn_out);
}

// Round 9
// 126.801 us; speedup vs baseline: 1.2417x; 1.0477x over previous
//
#include <hip/hip_runtime.h>
#include <hip/hip_bf16.h>
#include <math.h>

// Problem constants (from reference)
#define BATCH   2
#define SEQ     512     // N
#define DIN     512
#define DM      256     // d_model

#define LOG2E2  2.88539008177792681f   // 2*log2(e)

#if __has_builtin(__builtin_amdgcn_exp2f)
#define EXP2(x) __builtin_amdgcn_exp2f(x)
#else
#define EXP2(x) exp2f(x)
#endif
#if __has_builtin(__builtin_amdgcn_rcpf)
#define RCP(x) __builtin_amdgcn_rcpf(x)
#else
#define RCP(x) (1.0f / (x))
#endif

// tanh(t) with targ = 2*log2(e)*t: tanh = 1 - 2/(1 + exp2(targ)); overflow-safe.
__device__ __forceinline__ float tanh_from_scaled(float targ) {
    return fmaf(-2.0f, RCP(1.0f + EXP2(targ)), 1.0f);
}

// ---------------- Kernel 1: h = tanh(x@Wx+bx) + EA rows ----------------
// 512 blocks (2 rows each), 512 threads.
// EA part: thread = (r2 = tid>>8, d = tid&255) -> EA[row][d] = exp2(c*(pos_row.Wp_d + bp_d))
// h part: wave w = (r = w&1, kq = w>>1); 128-k quarter per wave; LDS partial combine.
__global__ __launch_bounds__(512) void h_ea_k(
    const float* __restrict__ pos,  // [B, N, 4]
    const float* __restrict__ Wp,   // [4, DM]
    const float* __restrict__ bp,   // [DM]
    const float* __restrict__ x,    // [B*N, DIN]
    const float* __restrict__ Wx,   // [DIN, DM]
    const float* __restrict__ bx,   // [DM]
    float* __restrict__ EA,         // [B*N, DM]
    float* __restrict__ h)          // [B*N, DM]
{
    __shared__ float4 s_x[2][DIN/4];       // 4 KB
    __shared__ float4 s_part[2][3][64];    // 6 KB

    const int tid = threadIdx.x;

    // ---- EA part (independent of h part; no barrier needed between them) ----
    {
        const int r2  = __builtin_amdgcn_readfirstlane(tid >> 8);   // 0/1
        const int d   = tid & 255;
        const int row = blockIdx.x * 2 + r2;
        const float4 p = ((const float4*)pos)[row];   // uniform -> s_load
        const float P = fmaf(p.x, Wp[d],
                        fmaf(p.y, Wp[DM + d],
                        fmaf(p.z, Wp[2*DM + d],
                             p.w * Wp[3*DM + d])));
        EA[(size_t)row * DM + d] = EXP2(LOG2E2 * (P + bp[d]));   // coalesced
    }

    // ---- h part ----
    const int w   = tid >> 6;
    const int l   = tid & 63;
    const int r   = w & 1;
    const int kq  = w >> 1;                // 0..3, 128-k quarter
    const int row = blockIdx.x * 2 + r;

    const float4* __restrict__ xr = (const float4*)(x + (size_t)row * DIN);
    s_x[r][kq * 32 + (l & 31)] = xr[kq * 32 + (l & 31)];
    __syncthreads();

    float4 acc = (kq == 0) ? ((const float4*)bx)[l] : make_float4(0.f, 0.f, 0.f, 0.f);
    const float* __restrict__ wxp = Wx + 4 * l;

    #pragma unroll 2
    for (int k4 = 0; k4 < 32; k4++) {
        const int kk = kq * 32 + k4;
        const float4 xv = s_x[r][kk];                     // ds_read_b128 broadcast
        const float4 w0 = *(const float4*)(wxp + (size_t)(4*kk + 0) * DM);
        const float4 w1 = *(const float4*)(wxp + (size_t)(4*kk + 1) * DM);
        const float4 w2 = *(const float4*)(wxp + (size_t)(4*kk + 2) * DM);
        const float4 w3 = *(const float4*)(wxp + (size_t)(4*kk + 3) * DM);
        acc.x = fmaf(xv.x, w0.x, acc.x); acc.y = fmaf(xv.x, w0.y, acc.y);
        acc.z = fmaf(xv.x, w0.z, acc.z); acc.w = fmaf(xv.x, w0.w, acc.w);
        acc.x = fmaf(xv.y, w1.x, acc.x); acc.y = fmaf(xv.y, w1.y, acc.y);
        acc.z = fmaf(xv.y, w1.z, acc.z); acc.w = fmaf(xv.y, w1.w, acc.w);
        acc.x = fmaf(xv.z, w2.x, acc.x); acc.y = fmaf(xv.z, w2.y, acc.y);
        acc.z = fmaf(xv.z, w2.z, acc.z); acc.w = fmaf(xv.z, w2.w, acc.w);
        acc.x = fmaf(xv.w, w3.x, acc.x); acc.y = fmaf(xv.w, w3.y, acc.y);
        acc.z = fmaf(xv.w, w3.z, acc.z); acc.w = fmaf(xv.w, w3.w, acc.w);
    }

    if (kq) s_part[r][kq - 1][l] = acc;
    __syncthreads();
    if (kq == 0) {
        const float4 q0 = s_part[r][0][l];
        const float4 q1 = s_part[r][1][l];
        const float4 q2 = s_part[r][2][l];
        float4 t;
        t.x = tanh_from_scaled(LOG2E2 * (acc.x + q0.x + q1.x + q2.x));
        t.y = tanh_from_scaled(LOG2E2 * (acc.y + q0.y + q1.y + q2.y));
        t.z = tanh_from_scaled(LOG2E2 * (acc.z + q0.z + q1.z + q2.z));
        t.w = tanh_from_scaled(LOG2E2 * (acc.w + q0.w + q1.w + q2.w));
        ((float4*)(h + (size_t)row * DM))[l] = t;
    }
}

// ---------------- Kernel 2: fused scores (eb inline) + softmax + weighted sum ----
// grid = B*N/4 = 256 blocks (4 i-rows each), 1024 threads (16 waves).
// Phase 1: thread = (j = tid&511, dh = tid>>9); dh-half owns 128 d's.
//   eb computed inline from pos_j (VGPR) x Wp (scalar streams); EA/wv scalar streams.
//   ZERO VMEM, ZERO LDS in the inner loop.
// Phase 3: p via wave-uniform s_load from attn_out; h read once (jq split).
__global__ __launch_bounds__(1024) void attn_kernel(
    const float* __restrict__ pos,   // [B, N, 4]
    const float* __restrict__ Wp,    // [4, DM]
    const int*   __restrict__ mask,  // [B, N, N]
    const float* __restrict__ wv,    // [DM]
    const float* __restrict__ EA,    // [B*N, DM]
    const float* __restrict__ h,     // [B, N, DM]
    float* __restrict__ out,         // [B, N, DM]
    float* __restrict__ attn_out)    // [B, N, N]
{
    const int b   = blockIdx.x >> 7;      // 128 blocks per batch
    const int i0  = (blockIdx.x & 127) * 4;
    const int tid = threadIdx.x;          // 0..1023
    const int l   = tid & 63;
    const int j   = tid & 511;
    const int dh  = __builtin_amdgcn_readfirstlane(tid >> 9);   // 0/1 -> d-half

    __shared__ float s_ap[4][SEQ];        // 8 KB: upper-half phase-1 partials
    __shared__ float s_o[3][4][DM];       // 12 KB: phase-3 partials
    __shared__ float s_red[4][8];

    // ---- phase 1: a_r[j] = sum_d w_d / (1 + EA[r,d] * exp2(-c*pos_j.Wp_d)) ----
    // score = const - 2a (softmax shift-invariant).
    const float4 pj = ((const float4*)pos)[b * SEQ + j];   // coalesced
    const float px = -LOG2E2 * pj.x, py = -LOG2E2 * pj.y,
                pz = -LOG2E2 * pj.z, pw = -LOG2E2 * pj.w;

    const int dbase = dh * 128;
    const float* __restrict__ wp0 = Wp + dbase;            // scalar streams
    const float* __restrict__ wp1 = Wp + DM + dbase;
    const float* __restrict__ wp2 = Wp + 2*DM + dbase;
    const float* __restrict__ wp3 = Wp + 3*DM + dbase;
    const float* __restrict__ wvp = wv + dbase;
    const float* __restrict__ ea0 = EA + (size_t)(b * SEQ + i0 + 0) * DM + dbase;
    const float* __restrict__ ea1 = ea0 + DM;
    const float* __restrict__ ea2 = ea0 + 2*DM;
    const float* __restrict__ ea3 = ea0 + 3*DM;

    float a0 = 0.f, a1 = 0.f, a2 = 0.f, a3 = 0.f;
    #pragma unroll 4
    for (int d = 0; d < 128; d++) {
        const float t  = fmaf(px, wp0[d], fmaf(py, wp1[d], fmaf(pz, wp2[d], pw * wp3[d])));
        const float eb = EXP2(t);
        const float wd = wvp[d];
        a0 = fmaf(wd, RCP(fmaf(ea0[d], eb, 1.0f)), a0);
        a1 = fmaf(wd, RCP(fmaf(ea1[d], eb, 1.0f)), a1);
        a2 = fmaf(wd, RCP(fmaf(ea2[d], eb, 1.0f)), a2);
        a3 = fmaf(wd, RCP(fmaf(ea3[d], eb, 1.0f)), a3);
    }

    if (dh == 1) {
        s_ap[0][j] = a0; s_ap[1][j] = a1; s_ap[2][j] = a2; s_ap[3][j] = a3;
    }
    __syncthreads();

    // ---- phase 2 (lower half only): masked softmax, no max-shift ----
    float p0, p1, p2, p3;
    size_t mrow0 = (size_t)b * SEQ * SEQ + (size_t)i0 * SEQ + j;
    if (dh == 0) {
        a0 += s_ap[0][j]; a1 += s_ap[1][j]; a2 += s_ap[2][j]; a3 += s_ap[3][j];

        const int m0 = mask[mrow0];
        const int m1 = mask[mrow0 + SEQ];
        const int m2 = mask[mrow0 + 2*SEQ];
        const int m3 = mask[mrow0 + 3*SEQ];
        p0 = m0 ? EXP2(-LOG2E2 * a0) : 0.f;
        p1 = m1 ? EXP2(-LOG2E2 * a1) : 0.f;
        p2 = m2 ? EXP2(-LOG2E2 * a2) : 0.f;
        p3 = m3 ? EXP2(-LOG2E2 * a3) : 0.f;

        float s0 = p0, s1 = p1, s2 = p2, s3 = p3;
        #pragma unroll
        for (int off = 32; off; off >>= 1) {
            s0 += __shfl_xor(s0, off, 64);
            s1 += __shfl_xor(s1, off, 64);
            s2 += __shfl_xor(s2, off, 64);
            s3 += __shfl_xor(s3, off, 64);
        }
        if (l == 0) {
            const int wj = tid >> 6;    // 0..7 for lower half
            s_red[0][wj] = s0; s_red[1][wj] = s1; s_red[2][wj] = s2; s_red[3][wj] = s3;
        }
    }
    __syncthreads();

    if (dh == 0) {
        const float4 r0a = ((const float4*)s_red[0])[0], r0b = ((const float4*)s_red[0])[1];
        const float4 r1a = ((const float4*)s_red[1])[0], r1b = ((const float4*)s_red[1])[1];
        const float4 r2a = ((const float4*)s_red[2])[0], r2b = ((const float4*)s_red[2])[1];
        const float4 r3a = ((const float4*)s_red[3])[0], r3b = ((const float4*)s_red[3])[1];
        p0 *= __fdividef(1.0f, (r0a.x+r0a.y+r0a.z+r0a.w) + (r0b.x+r0b.y+r0b.z+r0b.w));
        p1 *= __fdividef(1.0f, (r1a.x+r1a.y+r1a.z+r1a.w) + (r1b.x+r1b.y+r1b.z+r1b.w));
        p2 *= __fdividef(1.0f, (r2a.x+r2a.y+r2a.z+r2a.w) + (r2b.x+r2b.y+r2b.z+r2b.w));
        p3 *= __fdividef(1.0f, (r3a.x+r3a.y+r3a.z+r3a.w) + (r3b.x+r3b.y+r3b.z+r3b.w));

        attn_out[mrow0]         = p0;
        attn_out[mrow0 + SEQ]   = p1;
        attn_out[mrow0 + 2*SEQ] = p2;
        attn_out[mrow0 + 3*SEQ] = p3;
    }
    __syncthreads();   // attn_out visible to all waves before phase 3

    // ---- phase 3: out[i_r,d] = sum_j p_r[j] * h[b,j,d], all 16 waves ----
    // thread = (d = tid&255, jq = tid>>8 in 0..3 -> 128-j slice). p via s_load.
    const int jq = __builtin_amdgcn_readfirstlane(tid >> 8);
    const int d  = tid & 255;
    const float* __restrict__ hp = h + (size_t)(b * SEQ + jq * 128) * DM + d;
    const float* __restrict__ ar0 = attn_out + (size_t)b * SEQ * SEQ
                                  + (size_t)i0 * SEQ + jq * 128;   // wave-uniform base
    const float* __restrict__ ar1 = ar0 + SEQ;
    const float* __restrict__ ar2 = ar0 + 2*SEQ;
    const float* __restrict__ ar3 = ar0 + 3*SEQ;

    float c0 = 0.f, c1 = 0.f, c2 = 0.f, c3 = 0.f;
    #pragma unroll 2
    for (int q = 0; q < 32; q++) {
        const float4 P0 = *(const float4*)(ar0 + 4*q);   // s_load_dwordx4 (uniform)
        const float4 P1 = *(const float4*)(ar1 + 4*q);
        const float4 P2 = *(const float4*)(ar2 + 4*q);
        const float4 P3 = *(const float4*)(ar3 + 4*q);
        const float h0 = hp[(size_t)(4*q + 0) * DM];     // coalesced dword
        const float h1 = hp[(size_t)(4*q + 1) * DM];
        const float h2 = hp[(size_t)(4*q + 2) * DM];
        const float h3 = hp[(size_t)(4*q + 3) * DM];
        c0 = fmaf(P0.x, h0, fmaf(P0.y, h1, fmaf(P0.z, h2, fmaf(P0.w, h3, c0))));
        c1 = fmaf(P1.x, h0, fmaf(P1.y, h1, fmaf(P1.z, h2, fmaf(P1.w, h3, c1))));
        c2 = fmaf(P2.x, h0, fmaf(P2.y, h1, fmaf(P2.z, h2, fmaf(P2.w, h3, c2))));
        c3 = fmaf(P3.x, h0, fmaf(P3.y, h1, fmaf(P3.z, h2, fmaf(P3.w, h3, c3))));
    }

    if (jq > 0) {
        s_o[jq - 1][0][d] = c0;
        s_o[jq - 1][1][d] = c1;
        s_o[jq - 1][2][d] = c2;
        s_o[jq - 1][3][d] = c3;
    }
    __syncthreads();
    if (jq == 0) {
        float* __restrict__ op = out + (size_t)(b * SEQ + i0) * DM + d;
        op[0]    = c0 + s_o[0][0][d] + s_o[1][0][d] + s_o[2][0][d];
        op[DM]   = c1 + s_o[0][1][d] + s_o[1][1][d] + s_o[2][1][d];
        op[2*DM] = c2 + s_o[0][2][d] + s_o[1][2][d] + s_o[2][2][d];
        op[3*DM] = c3 + s_o[0][3][d] + s_o[1][3][d] + s_o[2][3][d];
    }
}

extern "C" void kernel_launch(void* const* d_in, const int* in_sizes, int n_in,
                              void* d_out, int out_size, void* d_ws, size_t ws_size,
                              hipStream_t stream) {
    const float* x    = (const float*)d_in[0];
    const float* pos  = (const float*)d_in[1];
    const int*   mask = (const int*)  d_in[2];
    const float* Wx   = (const float*)d_in[3];
    const float* bx   = (const float*)d_in[4];
    const float* Wp   = (const float*)d_in[5];
    const float* bp   = (const float*)d_in[6];
    const float* wv   = (const float*)d_in[7];

    float* out      = (float*)d_out;                          // [B,N,DM]
    float* attn_out = (float*)d_out + (size_t)BATCH*SEQ*DM;   // [B,N,N]

    char* ws  = (char*)d_ws;
    float* h  = (float*)(ws);                                 // 1 MB
    float* EA = (float*)(ws + (size_t)BATCH*SEQ*DM*4);        // 1 MB

    h_ea_k<<<(BATCH*SEQ)/2, 512, 0, stream>>>(pos, Wp, bp, x, Wx, bx, EA, h);
    attn_kernel<<<(BATCH*SEQ)/4, 1024, 0, stream>>>(pos, Wp, mask, wv, EA, h, out, attn_out);
}

// Round 10
// 119.604 us; speedup vs baseline: 1.3164x; 1.0602x over previous
//
#include <hip/hip_runtime.h>
#include <hip/hip_bf16.h>
#include <math.h>

// Problem constants (from reference)
#define BATCH   2
#define SEQ     512     // N
#define DIN     512
#define DM      256     // d_model

#define LOG2E2  2.88539008177792681f   // 2*log2(e)

#if __has_builtin(__builtin_amdgcn_exp2f)
#define EXP2(x) __builtin_amdgcn_exp2f(x)
#else
#define EXP2(x) exp2f(x)
#endif
#if __has_builtin(__builtin_amdgcn_rcpf)
#define RCP(x) __builtin_amdgcn_rcpf(x)
#else
#define RCP(x) (1.0f / (x))
#endif

// tanh(t) with targ = 2*log2(e)*t: tanh = 1 - 2/(1 + exp2(targ)); overflow-safe.
__device__ __forceinline__ float tanh_from_scaled(float targ) {
    return fmaf(-2.0f, RCP(1.0f + EXP2(targ)), 1.0f);
}

// ---------------- Kernel 1: EB2 pairs + EA rows + h = tanh(x@Wx+bx) ----------------
// 768 blocks x 512 threads.
//  blocks [0,256):   EB2[b][t][j] = {exp2(-c*P_{2t}(j)), exp2(-c*P_{2t+1}(j))}  (float2)
//  blocks [256,768): 2 rows each: EA[row][d] = exp2(c*(P_d(row)+bp_d)); h via 8-way k-split,
//                    each wave computes BOTH rows for its k-eighth (Wx read once).
__global__ __launch_bounds__(512) void prep_k(
    const float* __restrict__ pos,  // [B, N, 4]
    const float* __restrict__ Wp,   // [4, DM]
    const float* __restrict__ bp,   // [DM]
    const float* __restrict__ x,    // [B*N, DIN]
    const float* __restrict__ Wx,   // [DIN, DM]
    const float* __restrict__ bx,   // [DM]
    float* __restrict__ EA,         // [B*N, DM]
    float2* __restrict__ EB2,       // [B][128][SEQ] float2
    float* __restrict__ h)          // [B*N, DM]
{
    const int tid = threadIdx.x;

    if (blockIdx.x < 256) {
        // ---- EB2 part: block = (b, tg); d-pair (2tg, 2tg+1); thread = j ----
        const int b  = blockIdx.x >> 7;
        const int tg = blockIdx.x & 127;
        const int d0 = 2 * tg, d1 = d0 + 1;

        const float4 p = ((const float4*)pos)[b * SEQ + tid];   // coalesced 16B
        const float P0 = fmaf(p.x, Wp[d0], fmaf(p.y, Wp[DM + d0],
                         fmaf(p.z, Wp[2*DM + d0], p.w * Wp[3*DM + d0])));
        const float P1 = fmaf(p.x, Wp[d1], fmaf(p.y, Wp[DM + d1],
                         fmaf(p.z, Wp[2*DM + d1], p.w * Wp[3*DM + d1])));
        EB2[((size_t)(b * 128 + tg)) * SEQ + tid] =
            make_float2(EXP2(-LOG2E2 * P0), EXP2(-LOG2E2 * P1));   // coalesced 8B
        return;
    }

    // ---- h + EA part: rows row0, row0+1 ----
    __shared__ float4 s_x[2][DIN/4];       // 4 KB
    __shared__ float4 s_part[2][7][64];    // 14 KB

    const int row0 = (blockIdx.x - 256) * 2;

    // EA (independent of h; no barrier needed before staging)
    {
        const int r2  = __builtin_amdgcn_readfirstlane(tid >> 8);   // 0/1
        const int d   = tid & 255;
        const int row = row0 + r2;
        const float4 p = ((const float4*)pos)[row];   // uniform -> s_load
        const float P = fmaf(p.x, Wp[d],
                        fmaf(p.y, Wp[DM + d],
                        fmaf(p.z, Wp[2*DM + d],
                             p.w * Wp[3*DM + d])));
        EA[(size_t)row * DM + d] = EXP2(LOG2E2 * (P + bp[d]));   // coalesced
    }

    // stage both x rows (coalesced float4)
    if (tid < 256) {
        const int r   = tid >> 7;
        const int idx = tid & 127;
        s_x[r][idx] = ((const float4*)(x + (size_t)(row0 + r) * DIN))[idx];
    }
    __syncthreads();

    const int w = tid >> 6;        // k-eighth 0..7
    const int l = tid & 63;        // lane -> cols 4l..4l+3

    float4 acc0 = make_float4(0.f, 0.f, 0.f, 0.f);
    float4 acc1 = make_float4(0.f, 0.f, 0.f, 0.f);
    const float* __restrict__ wxp = Wx + 4 * l;

    #pragma unroll 2
    for (int k4 = 0; k4 < 16; k4++) {
        const int kk = w * 16 + k4;
        const float4 xv0 = s_x[0][kk];                    // ds_read_b128 broadcast
        const float4 xv1 = s_x[1][kk];
        const float4 w0 = *(const float4*)(wxp + (size_t)(4*kk + 0) * DM);
        const float4 w1 = *(const float4*)(wxp + (size_t)(4*kk + 1) * DM);
        const float4 w2 = *(const float4*)(wxp + (size_t)(4*kk + 2) * DM);
        const float4 w3 = *(const float4*)(wxp + (size_t)(4*kk + 3) * DM);
        acc0.x = fmaf(xv0.x, w0.x, acc0.x); acc0.y = fmaf(xv0.x, w0.y, acc0.y);
        acc0.z = fmaf(xv0.x, w0.z, acc0.z); acc0.w = fmaf(xv0.x, w0.w, acc0.w);
        acc0.x = fmaf(xv0.y, w1.x, acc0.x); acc0.y = fmaf(xv0.y, w1.y, acc0.y);
        acc0.z = fmaf(xv0.y, w1.z, acc0.z); acc0.w = fmaf(xv0.y, w1.w, acc0.w);
        acc0.x = fmaf(xv0.z, w2.x, acc0.x); acc0.y = fmaf(xv0.z, w2.y, acc0.y);
        acc0.z = fmaf(xv0.z, w2.z, acc0.z); acc0.w = fmaf(xv0.z, w2.w, acc0.w);
        acc0.x = fmaf(xv0.w, w3.x, acc0.x); acc0.y = fmaf(xv0.w, w3.y, acc0.y);
        acc0.z = fmaf(xv0.w, w3.z, acc0.z); acc0.w = fmaf(xv0.w, w3.w, acc0.w);
        acc1.x = fmaf(xv1.x, w0.x, acc1.x); acc1.y = fmaf(xv1.x, w0.y, acc1.y);
        acc1.z = fmaf(xv1.x, w0.z, acc1.z); acc1.w = fmaf(xv1.x, w0.w, acc1.w);
        acc1.x = fmaf(xv1.y, w1.x, acc1.x); acc1.y = fmaf(xv1.y, w1.y, acc1.y);
        acc1.z = fmaf(xv1.y, w1.z, acc1.z); acc1.w = fmaf(xv1.y, w1.w, acc1.w);
        acc1.x = fmaf(xv1.z, w2.x, acc1.x); acc1.y = fmaf(xv1.z, w2.y, acc1.y);
        acc1.z = fmaf(xv1.z, w2.z, acc1.z); acc1.w = fmaf(xv1.z, w2.w, acc1.w);
        acc1.x = fmaf(xv1.w, w3.x, acc1.x); acc1.y = fmaf(xv1.w, w3.y, acc1.y);
        acc1.z = fmaf(xv1.w, w3.z, acc1.z); acc1.w = fmaf(xv1.w, w3.w, acc1.w);
    }

    if (w) {
        s_part[0][w - 1][l] = acc0;
        s_part[1][w - 1][l] = acc1;
    }
    __syncthreads();
    if (w == 0) {
        const float4 b4 = ((const float4*)bx)[l];
        acc0.x += b4.x; acc0.y += b4.y; acc0.z += b4.z; acc0.w += b4.w;
        acc1.x += b4.x; acc1.y += b4.y; acc1.z += b4.z; acc1.w += b4.w;
        #pragma unroll
        for (int q = 0; q < 7; q++) {
            const float4 q0 = s_part[0][q][l];
            const float4 q1 = s_part[1][q][l];
            acc0.x += q0.x; acc0.y += q0.y; acc0.z += q0.z; acc0.w += q0.w;
            acc1.x += q1.x; acc1.y += q1.y; acc1.z += q1.z; acc1.w += q1.w;
        }
        float4 t0, t1;
        t0.x = tanh_from_scaled(LOG2E2 * acc0.x);
        t0.y = tanh_from_scaled(LOG2E2 * acc0.y);
        t0.z = tanh_from_scaled(LOG2E2 * acc0.z);
        t0.w = tanh_from_scaled(LOG2E2 * acc0.w);
        t1.x = tanh_from_scaled(LOG2E2 * acc1.x);
        t1.y = tanh_from_scaled(LOG2E2 * acc1.y);
        t1.z = tanh_from_scaled(LOG2E2 * acc1.z);
        t1.w = tanh_from_scaled(LOG2E2 * acc1.w);
        ((float4*)(h + (size_t)row0 * DM))[l]       = t0;
        ((float4*)(h + (size_t)(row0 + 1) * DM))[l] = t1;
    }
}

// ---------------- Kernel 2: scores + softmax + weighted sum ----------------
// 256 blocks (4 i-rows each) x 1024 threads (16 waves).
// Phase 1: thread = (j = tid&511, rg = tid>>9 -> rows {i0+2rg, i0+2rg+1}).
//   Per d-PAIR: 1 ds_read_b128 broadcast (4 EA) + 1 coalesced dwordx2 (EB pair)
//   + pair-merged rcp:  w0/y0 + w1/y1 = (w0*y1 + w1*y0) / (y0*y1)  -> 1 rcp per row.
__global__ __launch_bounds__(1024) void attn_k(
    const int*   __restrict__ mask,  // [B, N, N]
    const float* __restrict__ wv,    // [DM]
    const float* __restrict__ EA,    // [B*N, DM]
    const float2* __restrict__ EB2,  // [B][128][SEQ]
    const float* __restrict__ h,     // [B, N, DM]
    float* __restrict__ out,         // [B, N, DM]
    float* __restrict__ attn_out)    // [B, N, N]
{
    const int b   = blockIdx.x >> 7;
    const int i0  = (blockIdx.x & 127) * 4;
    const int tid = threadIdx.x;
    const int l   = tid & 63;
    const int j   = tid & 511;
    const int rg  = __builtin_amdgcn_readfirstlane(tid >> 9);   // 0/1

    __shared__ float4 s_ea[128][2];   // {eaA_d0, eaA_d1, eaB_d0, eaB_d1} : 4 KB
    __shared__ float  s_o[3][4][DM];  // 12 KB phase-3 partials
    __shared__ float  s_red[4][8];

    // stage EA pairs: t = tid>>1, g = tid&1; rows (i0+2g, i0+2g+1)
    if (tid < 256) {
        const int t = tid >> 1;
        const int g = tid & 1;
        const float2 ea_a = *(const float2*)(EA + (size_t)(b * SEQ + i0 + 2*g) * DM + 2*t);
        const float2 ea_b = *(const float2*)(EA + (size_t)(b * SEQ + i0 + 2*g + 1) * DM + 2*t);
        s_ea[t][g] = make_float4(ea_a.x, ea_a.y, ea_b.x, ea_b.y);
    }
    __syncthreads();

    // ---- phase 1 ----
    const float2* __restrict__ EBj = EB2 + (size_t)b * 128 * SEQ + j;
    const float4* __restrict__ eap = &s_ea[0][rg];

    float aA = 0.f, aB = 0.f;
    #pragma unroll 8
    for (int t = 0; t < 128; t++) {
        const float2 eb = EBj[(size_t)t * SEQ];   // coalesced dwordx2 (L2)
        const float4 q  = eap[2 * t];             // ds_read_b128 broadcast
        const float  w0 = wv[2*t];                // scalar stream
        const float  w1 = wv[2*t + 1];
        const float yA0 = fmaf(q.x, eb.x, 1.0f);
        const float yA1 = fmaf(q.y, eb.y, 1.0f);
        const float yB0 = fmaf(q.z, eb.x, 1.0f);
        const float yB1 = fmaf(q.w, eb.y, 1.0f);
        aA = fmaf(fmaf(w1, yA0, w0 * yA1), RCP(yA0 * yA1), aA);
        aB = fmaf(fmaf(w1, yB0, w0 * yB1), RCP(yB0 * yB1), aB);
    }

    // ---- phase 2: masked softmax (score = const - 2a; shift-invariant) ----
    const size_t mrowA = (size_t)b * SEQ * SEQ + (size_t)(i0 + 2*rg) * SEQ + j;
    const int mA = mask[mrowA];
    const int mB = mask[mrowA + SEQ];

    float pA = mA ? EXP2(-LOG2E2 * aA) : 0.f;
    float pB = mB ? EXP2(-LOG2E2 * aB) : 0.f;

    float sA = pA, sB = pB;
    #pragma unroll
    for (int off = 32; off; off >>= 1) {
        sA += __shfl_xor(sA, off, 64);
        sB += __shfl_xor(sB, off, 64);
    }
    const int w = tid >> 6;   // 0..15
    if (l == 0) {
        s_red[2*rg][w & 7]     = sA;
        s_red[2*rg + 1][w & 7] = sB;
    }
    __syncthreads();

    const float4 ra = ((const float4*)s_red[2*rg])[0],     rb = ((const float4*)s_red[2*rg])[1];
    const float4 rc = ((const float4*)s_red[2*rg + 1])[0], rd = ((const float4*)s_red[2*rg + 1])[1];
    pA *= __fdividef(1.0f, (ra.x+ra.y+ra.z+ra.w) + (rb.x+rb.y+rb.z+rb.w));
    pB *= __fdividef(1.0f, (rc.x+rc.y+rc.z+rc.w) + (rd.x+rd.y+rd.z+rd.w));

    attn_out[mrowA]       = pA;
    attn_out[mrowA + SEQ] = pB;
    __syncthreads();   // attn_out visible before phase 3

    // ---- phase 3: out[i_r,d] = sum_j p_r[j] * h[b,j,d] ----
    const int jq = __builtin_amdgcn_readfirstlane(tid >> 8);   // 0..3 -> 128-j slice
    const int d  = tid & 255;
    const float* __restrict__ hp  = h + (size_t)(b * SEQ + jq * 128) * DM + d;
    const float* __restrict__ ar0 = attn_out + (size_t)b * SEQ * SEQ
                                  + (size_t)i0 * SEQ + jq * 128;   // wave-uniform
    const float* __restrict__ ar1 = ar0 + SEQ;
    const float* __restrict__ ar2 = ar0 + 2*SEQ;
    const float* __restrict__ ar3 = ar0 + 3*SEQ;

    float c0 = 0.f, c1 = 0.f, c2 = 0.f, c3 = 0.f;
    #pragma unroll 2
    for (int q = 0; q < 32; q++) {
        const float4 P0 = *(const float4*)(ar0 + 4*q);   // uniform loads
        const float4 P1 = *(const float4*)(ar1 + 4*q);
        const float4 P2 = *(const float4*)(ar2 + 4*q);
        const float4 P3 = *(const float4*)(ar3 + 4*q);
        const float h0 = hp[(size_t)(4*q + 0) * DM];     // coalesced dword
        const float h1 = hp[(size_t)(4*q + 1) * DM];
        const float h2 = hp[(size_t)(4*q + 2) * DM];
        const float h3 = hp[(size_t)(4*q + 3) * DM];
        c0 = fmaf(P0.x, h0, fmaf(P0.y, h1, fmaf(P0.z, h2, fmaf(P0.w, h3, c0))));
        c1 = fmaf(P1.x, h0, fmaf(P1.y, h1, fmaf(P1.z, h2, fmaf(P1.w, h3, c1))));
        c2 = fmaf(P2.x, h0, fmaf(P2.y, h1, fmaf(P2.z, h2, fmaf(P2.w, h3, c2))));
        c3 = fmaf(P3.x, h0, fmaf(P3.y, h1, fmaf(P3.z, h2, fmaf(P3.w, h3, c3))));
    }

    if (jq > 0) {
        s_o[jq - 1][0][d] = c0;
        s_o[jq - 1][1][d] = c1;
        s_o[jq - 1][2][d] = c2;
        s_o[jq - 1][3][d] = c3;
    }
    __syncthreads();
    if (jq == 0) {
        float* __restrict__ op = out + (size_t)(b * SEQ + i0) * DM + d;
        op[0]    = c0 + s_o[0][0][d] + s_o[1][0][d] + s_o[2][0][d];
        op[DM]   = c1 + s_o[0][1][d] + s_o[1][1][d] + s_o[2][1][d];
        op[2*DM] = c2 + s_o[0][2][d] + s_o[1][2][d] + s_o[2][2][d];
        op[3*DM] = c3 + s_o[0][3][d] + s_o[1][3][d] + s_o[2][3][d];
    }
}

extern "C" void kernel_launch(void* const* d_in, const int* in_sizes, int n_in,
                              void* d_out, int out_size, void* d_ws, size_t ws_size,
                              hipStream_t stream) {
    const float* x    = (const float*)d_in[0];
    const float* pos  = (const float*)d_in[1];
    const int*   mask = (const int*)  d_in[2];
    const float* Wx   = (const float*)d_in[3];
    const float* bx   = (const float*)d_in[4];
    const float* Wp   = (const float*)d_in[5];
    const float* bp   = (const float*)d_in[6];
    const float* wv   = (const float*)d_in[7];

    float* out      = (float*)d_out;                          // [B,N,DM]
    float* attn_out = (float*)d_out + (size_t)BATCH*SEQ*DM;   // [B,N,N]

    char*   ws  = (char*)d_ws;
    float*  h   = (float*)(ws);                               // 1 MB
    float*  EA  = (float*)(ws + (size_t)BATCH*SEQ*DM*4);      // 1 MB
    float2* EB2 = (float2*)(ws + 2*(size_t)BATCH*SEQ*DM*4);   // 1 MB

    prep_k<<<256 + (BATCH*SEQ)/2, 512, 0, stream>>>(pos, Wp, bp, x, Wx, bx, EA, EB2, h);
    attn_k<<<(BATCH*SEQ)/4, 1024, 0, stream>>>(mask, wv, EA, EB2, h, out, attn_out);
}